// Round 3
// baseline (1416.287 us; speedup 1.0000x reference)
//
#include <hip/hip_runtime.h>
#include <cstdint>
#include <cmath>

using u16 = unsigned short;
using u8  = unsigned char;
using u32 = unsigned int;

typedef __attribute__((ext_vector_type(8))) short short8;
typedef __attribute__((ext_vector_type(8))) unsigned short u16x8;
typedef __attribute__((ext_vector_type(4))) unsigned short u16x4;
typedef __attribute__((ext_vector_type(4))) float f32x4;

#define DEV static __device__ __forceinline__

DEV u16 f2bf(float f) {               // fp32 -> bf16 RNE
  u32 u = __builtin_bit_cast(u32, f);
  u = u + 0x7fffu + ((u >> 16) & 1u);
  return (u16)(u >> 16);
}
DEV float bf2f(u16 h) { return __builtin_bit_cast(float, ((u32)h) << 16); }

// ---------------- wave-local GEMM: one wave computes 16 rows x (NT*16) cols.
// B loaded DIRECTLY global->VGPR from packed fragment order (16 lanes read 256B contiguous,
// L1/L2 resident). A read from wave-local LDS. 16x16x32 layouts:
// A[m=lane&15][k=quad*8+j], B[k=quad*8+j][n=lane&15], C row=quad*4+reg, col=lane&15.
// NO barriers: all LDS traffic is wave-local, in-order within the wave.
template<int NT, int NKB>
DEV void gemm_wave(const u16* __restrict__ wsrc, int ncols,
                   const u16* actp, int strideA, int kbase,
                   f32x4* acc, int lane) {
  int l15 = lane & 15, quad = lane >> 4;
  const u16* arow = actp + l15 * strideA + kbase + quad*8;
#pragma unroll
  for (int kb = 0; kb < NKB; ++kb) {
    short8 af = *(const short8*)(arow + kb*32);
    const u16* wrow = wsrc + (size_t)(kb*4 + quad) * ncols * 8;
#pragma unroll
    for (int t = 0; t < NT; ++t) {
      short8 bf = *(const short8*)(wrow + (t*16 + l15) * 8);
      acc[t] = __builtin_amdgcn_mfma_f32_16x16x32_bf16(af, bf, acc[t], 0, 0, 0);
    }
  }
}

// ---------------- epilogues (all wave-local, zero barriers) ----------------
// LayerNorm over full 128-col rows owned by this wave: 16-lane butterfly gives exact
// row sums. fp32 residual rxf[8][4] lives in registers. Writes bf16 post-LN into act.
DEV void ln_epi8(f32x4* acc, float rxf[8][4], int l15, int quad,
                 const float* __restrict__ bias, const float* __restrict__ g,
                 const float* __restrict__ be, u16* actp) {
  float v[8][4];
  float s[4] = {0.f,0.f,0.f,0.f}, ss[4] = {0.f,0.f,0.f,0.f};
#pragma unroll
  for (int t = 0; t < 8; ++t) {
    int col = t*16 + l15;
    float b = bias[col];
#pragma unroll
    for (int r = 0; r < 4; ++r) {
      float val = acc[t][r] + b + rxf[t][r];
      v[t][r] = val;
      s[r] += val; ss[r] += val*val;
    }
  }
#pragma unroll
  for (int m = 1; m < 16; m <<= 1) {
#pragma unroll
    for (int r = 0; r < 4; ++r) {
      s[r]  += __shfl_xor(s[r],  m);
      ss[r] += __shfl_xor(ss[r], m);
    }
  }
#pragma unroll
  for (int r = 0; r < 4; ++r) {
    int row = quad*4 + r;
    float mean = s[r] * (1.f/128.f);
    float var  = ss[r] * (1.f/128.f) - mean*mean;
    float rs = rsqrtf(var + 1e-5f);
#pragma unroll
    for (int t = 0; t < 8; ++t) {
      int col = t*16 + l15;
      float xn = (v[t][r] - mean) * rs * g[col] + be[col];
      rxf[t][r] = xn;
      actp[row*136 + col] = f2bf(xn);
    }
  }
}

DEV void relu_epi8(f32x4* acc, int l15, int quad,
                   const float* __restrict__ bias, int colbase, u16* hb) {
#pragma unroll
  for (int t = 0; t < 8; ++t) {
    int col = t*16 + l15;
    float b = bias[colbase + col];
#pragma unroll
    for (int r = 0; r < 4; ++r) {
      int row = quad*4 + r;
      hb[row*264 + colbase + col] = f2bf(fmaxf(acc[t][r] + b, 0.f));
    }
  }
}

DEV void q_epi8(f32x4* acc, int l15, int quad, u16* hb) {
#pragma unroll
  for (int t = 0; t < 8; ++t)
#pragma unroll
    for (int r = 0; r < 4; ++r)
      hb[(quad*4 + r)*264 + t*16 + l15] = f2bf(acc[t][r]);
}

// ---------------- attention: wave-local; 16 nodes x 8 heads = 128 items, 2 per lane
DEV void attention_wave(const u16* __restrict__ Pg, const int* nidx, const u8* nval,
                        const u16* qb, u16* actp, int layerOff, int lane) {
#pragma unroll
  for (int p = 0; p < 2; ++p) {
    int nl = p*8 + (lane >> 3);
    int hd = lane & 7;
    float q[16];
    {
      const u16* qp = qb + nl*264 + hd*16;
      u16x8 q0 = *(const u16x8*)qp;
      u16x8 q1 = *(const u16x8*)(qp + 8);
#pragma unroll
      for (int i = 0; i < 8; ++i) { q[i] = bf2f(q0[i]); q[8+i] = bf2f(q1[i]); }
    }
    float sc[5], w[5];
    int mlist[5], vmask[5];
    float mx = -1e30f;
#pragma unroll
    for (int j = 0; j < 5; ++j) {
      int mj = nidx[nl*5 + j];
      int vj = nval[nl*5 + j];
      mlist[j] = mj; vmask[j] = vj;
      const u16* kr = Pg + (size_t)mj*512 + layerOff + hd*16;
      u16x8 k0 = *(const u16x8*)kr;
      u16x8 k1 = *(const u16x8*)(kr + 8);
      float d = 0.f;
#pragma unroll
      for (int i = 0; i < 8; ++i) d += bf2f(k0[i])*q[i] + bf2f(k1[i])*q[8+i];
      sc[j] = vj ? d * 0.25f : -1e30f;          // dh^-0.5 = 0.25
      mx = fmaxf(mx, sc[j]);
    }
    int anyv = vmask[0] | vmask[1] | vmask[2] | vmask[3] | vmask[4];
    float sum = 0.f;
#pragma unroll
    for (int j = 0; j < 5; ++j) { w[j] = vmask[j] ? __expf(sc[j] - mx) : 0.f; sum += w[j]; }
    float o[16];
#pragma unroll
    for (int i = 0; i < 16; ++i) o[i] = 0.f;
    if (anyv) {
      float inv = 1.f / sum;
#pragma unroll
      for (int j = 0; j < 5; ++j) {
        if (w[j] > 0.f) {
          const u16* vr = Pg + (size_t)mlist[j]*512 + layerOff + 128 + hd*16;
          u16x8 v0 = *(const u16x8*)vr;
          u16x8 v1 = *(const u16x8*)(vr + 8);
          float wj = w[j] * inv;
#pragma unroll
          for (int i = 0; i < 8; ++i) { o[i] += wj * bf2f(v0[i]); o[8+i] += wj * bf2f(v1[i]); }
        }
      }
    }
    u16* op = actp + nl*136 + hd*16;
#pragma unroll
    for (int i = 0; i < 16; ++i) op[i] = f2bf(o[i]);
  }
}

// cooperative wave-local feat staging: 16 rows x 128 fp32 -> bf16 LDS (vectorized)
DEV void stage_feat_wave(const float* __restrict__ feat, int nb, int N, u16* actp, int lane) {
#pragma unroll
  for (int it = 0; it < 8; ++it) {
    int i = it*64 + lane;            // 0..511 float4 slots
    int row = i >> 5, c4 = i & 31;
    int n = nb + row;
    float4 f = {0.f,0.f,0.f,0.f};
    if (n < N) f = *(const float4*)(feat + (size_t)n*128 + c4*4);
    u16x4 v4 = { f2bf(f.x), f2bf(f.y), f2bf(f.z), f2bf(f.w) };
    *(u16x4*)(actp + row*136 + c4*4) = v4;
  }
}

// ---------------- kernel 1: P[n] = [feat@wk1 | feat@wv1 | feat@wk2 | feat@wv2] (bf16)
// 4 independent waves x 16 rows, ZERO barriers.
__global__ __launch_bounds__(256) void k1_proj(const float* __restrict__ feat,
                                               u16* __restrict__ P,
                                               const u16* __restrict__ wpack, int N) {
  __shared__ __align__(16) u16 s_act[4*16*136];
  __shared__ __align__(16) u16 s_c[4*16*128];
  int tid = threadIdx.x, wave = tid >> 6, lane = tid & 63;
  int l15 = lane & 15, quad = lane >> 4;
  u16* actp = s_act + wave*16*136;
  u16* cbuf = s_c   + wave*16*128;
  int nb = blockIdx.x*64 + wave*16;

  stage_feat_wave(feat, nb, N, actp, lane);

  f32x4 z = {0.f,0.f,0.f,0.f};
  for (int wsel = 0; wsel < 4; ++wsel) {
    f32x4 acc[8] = {z,z,z,z,z,z,z,z};
    gemm_wave<8,4>(wpack + (size_t)(1 + wsel)*16384, 128, actp, 136, 0, acc, lane);
#pragma unroll
    for (int t = 0; t < 8; ++t)
#pragma unroll
      for (int r = 0; r < 4; ++r)
        cbuf[(quad*4 + r)*128 + t*16 + l15] = f2bf(acc[t][r]);
    // wave-local coalesced 16B stores: 256 uint4 / 64 lanes = 4 each
    const uint4* src = (const uint4*)cbuf;
#pragma unroll
    for (int it = 0; it < 4; ++it) {
      int i = it*64 + lane;
      int row = i >> 4, c8 = i & 15;
      int n = nb + row;
      if (n < N) *(uint4*)(P + (size_t)n*512 + wsel*128 + c8*8) = src[i];
    }
  }
}

// ---------------- kernel 2: fused two transformer blocks + head.
// 4 independent waves x 16 nodes per block, ZERO __syncthreads.
struct K2Args {
  const float* feat; const int* nidx; const void* nval; const int* flag;
  const u16* P; const u16* wpack;
  const float* bo1; const float* b1a; const float* b1b;
  const float* g1a; const float* be1a; const float* g1b; const float* be1b;
  const float* bo2; const float* b2a; const float* b2b;
  const float* g2a; const float* be2a; const float* g2b; const float* be2b;
  const float* b4; float* out; int N;
};

__global__ __launch_bounds__(256) void k2_fused(K2Args a) {
  __shared__ __align__(16) u16 s_act[4*16*136];  // bf16 activation (MFMA A), per wave
  __shared__ __align__(16) u16 s_h[4*16*264];    // q buffer / FFN hidden, per wave
  __shared__ int s_nidx[4*80];
  __shared__ u8  s_nval[4*80];

  int tid = threadIdx.x, wave = tid >> 6, lane = tid & 63;
  int l15 = lane & 15, quad = lane >> 4;
  u16* actp = s_act + wave*16*136;
  u16* hb   = s_h   + wave*16*264;
  int* wn_i = s_nidx + wave*80;
  u8*  wn_v = s_nval + wave*80;
  int nb = blockIdx.x*64 + wave*16;

  stage_feat_wave(a.feat, nb, a.N, actp, lane);

  { // neighbor meta, wave-local (encoding-agnostic via flag)
    int mode = *a.flag;
    for (int i = lane; i < 80; i += 64) {
      int n2 = nb + i/5;
      int idx = 0; u8 val = 0;
      if (n2 < a.N) {
        size_t e = (size_t)nb*5 + i;
        idx = a.nidx[e];
        if (mode == 0)      val = (((const int*)a.nval)[e]   != 0);
        else if (mode == 1) val = (((const float*)a.nval)[e] != 0.f);
        else                val = (((const u8*)a.nval)[e]    != 0);
      }
      wn_i[i] = idx; wn_v[i] = val;
    }
  }

  float rxf[8][4];   // fp32 residual, C-layout: row=quad*4+r, col=t*16+l15
#pragma unroll
  for (int t = 0; t < 8; ++t) {
    int col = t*16 + l15;
#pragma unroll
    for (int r = 0; r < 4; ++r) {
      int n = nb + quad*4 + r;
      rxf[t][r] = (n < a.N) ? a.feat[(size_t)n*128 + col] : 0.f;  // L1-hot re-read
    }
  }

  f32x4 z = {0.f,0.f,0.f,0.f};
  const u16* wp = a.wpack;

  { // q1 = x @ wq1 -> hb
    f32x4 acc[8] = {z,z,z,z,z,z,z,z};
    gemm_wave<8,4>(wp + 0, 128, actp, 136, 0, acc, lane);
    q_epi8(acc, l15, quad, hb);
  }
  attention_wave(a.P, wn_i, wn_v, hb, actp, 0, lane);
  { // @wo1 + bo1 + resid -> LN1a
    f32x4 acc[8] = {z,z,z,z,z,z,z,z};
    gemm_wave<8,4>(wp + (size_t)5*16384, 128, actp, 136, 0, acc, lane);
    ln_epi8(acc, rxf, l15, quad, a.bo1, a.g1a, a.be1a, actp);
  }
  { // FFN1 up: relu(x@w1a+b1a), 2 col halves
    f32x4 acc[8] = {z,z,z,z,z,z,z,z};
    gemm_wave<8,4>(wp + (size_t)6*16384, 128, actp, 136, 0, acc, lane);
    relu_epi8(acc, l15, quad, a.b1a, 0, hb);
    f32x4 acc2[8] = {z,z,z,z,z,z,z,z};
    gemm_wave<8,4>(wp + (size_t)7*16384, 128, actp, 136, 0, acc2, lane);
    relu_epi8(acc2, l15, quad, a.b1a, 128, hb);
  }
  { // FFN1 down (K=256) + resid -> LN1b => x1
    f32x4 acc[8] = {z,z,z,z,z,z,z,z};
    gemm_wave<8,4>(wp + (size_t)8*16384, 128, hb, 264, 0,   acc, lane);
    gemm_wave<8,4>(wp + (size_t)9*16384, 128, hb, 264, 128, acc, lane);
    ln_epi8(acc, rxf, l15, quad, a.b1b, a.g1b, a.be1b, actp);
  }
  { // q2 = x1 @ wq2 -> hb
    f32x4 acc[8] = {z,z,z,z,z,z,z,z};
    gemm_wave<8,4>(wp + (size_t)10*16384, 128, actp, 136, 0, acc, lane);
    q_epi8(acc, l15, quad, hb);
  }
  attention_wave(a.P, wn_i, wn_v, hb, actp, 256, lane);  // k2/v2 at u16 offsets 256/384
  { // @wo2 + bo2 + resid -> LN2a
    f32x4 acc[8] = {z,z,z,z,z,z,z,z};
    gemm_wave<8,4>(wp + (size_t)11*16384, 128, actp, 136, 0, acc, lane);
    ln_epi8(acc, rxf, l15, quad, a.bo2, a.g2a, a.be2a, actp);
  }
  { // FFN2 up
    f32x4 acc[8] = {z,z,z,z,z,z,z,z};
    gemm_wave<8,4>(wp + (size_t)12*16384, 128, actp, 136, 0, acc, lane);
    relu_epi8(acc, l15, quad, a.b2a, 0, hb);
    f32x4 acc2[8] = {z,z,z,z,z,z,z,z};
    gemm_wave<8,4>(wp + (size_t)13*16384, 128, actp, 136, 0, acc2, lane);
    relu_epi8(acc2, l15, quad, a.b2a, 128, hb);
  }
  { // FFN2 down + resid -> LN2b => out2
    f32x4 acc[8] = {z,z,z,z,z,z,z,z};
    gemm_wave<8,4>(wp + (size_t)14*16384, 128, hb, 264, 0,   acc, lane);
    gemm_wave<8,4>(wp + (size_t)15*16384, 128, hb, 264, 128, acc, lane);
    ln_epi8(acc, rxf, l15, quad, a.b2b, a.g2b, a.be2b, actp);
  }
  { // head: tanh(out2 @ w4 + b4) -> out (N x 64 fp32)
    f32x4 acc[4] = {z,z,z,z};
    gemm_wave<4,4>(wp + (size_t)16*16384, 64, actp, 136, 0, acc, lane);
#pragma unroll
    for (int t = 0; t < 4; ++t) {
      int col = t*16 + l15;
      float b = a.b4[col];
#pragma unroll
      for (int r = 0; r < 4; ++r) {
        int n = nb + quad*4 + r;
        if (n < a.N) a.out[(size_t)n*64 + col] = tanhf(acc[t][r] + b);
      }
    }
  }
}

// ---------------- weight pack: fp32 -> bf16 in MFMA-B-fragment-swizzled order
struct PackDesc { const float* src; int srcStride; int row0; int col0; int ncols; int dstOff; };
struct PackArgs { PackDesc d[17]; };

__global__ void pack_kernel(PackArgs pa, u16* __restrict__ wpack) {
  PackDesc d = pa.d[blockIdx.x];
  int total = 128 * d.ncols;
  for (int e = threadIdx.x; e < total; e += blockDim.x) {
    int k, n;
    if (d.ncols == 128) { k = e >> 7; n = e & 127; }
    else                { k = e >> 6; n = e & 63; }
    float v = d.src[(size_t)(d.row0 + k) * d.srcStride + d.col0 + n];
    int kb = k >> 5, q = (k >> 3) & 3, j = k & 7;
    wpack[d.dstOff + ((kb*4 + q) * d.ncols + n) * 8 + j] = f2bf(v);
  }
}

// ---------------- nbr_valid encoding detection (memory-safe for byte/int32/fp32 encodings)
__global__ void detect_kernel(const u32* __restrict__ nv, int* __restrict__ flag) {
  __shared__ int sInt, sFlt;
  if (threadIdx.x == 0) { sInt = 1; sFlt = 1; }
  __syncthreads();
  int okI = 1, okF = 1;
  for (int i = threadIdx.x; i < 2048; i += blockDim.x) {
    u32 w = nv[i];
    if (w > 1u) okI = 0;
    if (w != 0u && w != 0x3F800000u) okF = 0;
  }
  if (!okI) atomicAnd(&sInt, 0);
  if (!okF) atomicAnd(&sFlt, 0);
  __syncthreads();
  if (threadIdx.x == 0) *flag = sInt ? 0 : (sFlt ? 1 : 2);
}

extern "C" void kernel_launch(void* const* d_in, const int* in_sizes, int n_in,
                              void* d_out, int out_size, void* d_ws, size_t ws_size,
                              hipStream_t stream) {
  const float* feat = (const float*)d_in[0];
  const int*   nidx = (const int*)d_in[1];
  const void*  nval = d_in[2];
  int N = in_sizes[0] / 128;

  // workspace: P (N x 512 bf16 = 307 MB) | 17 packed weight chunks | flag
  u16* P     = (u16*)d_ws;
  u16* wpack = P + (size_t)N * 512;
  int* flag  = (int*)(wpack + (size_t)17 * 16384);

  detect_kernel<<<1, 256, 0, stream>>>((const u32*)nval, flag);

  PackArgs pa;
  int c = 0;
  auto W = [&](int i){ return (const float*)d_in[i]; };
  auto add = [&](const float* src, int stride, int r0, int c0, int ncols){
    pa.d[c] = PackDesc{src, stride, r0, c0, ncols, c * 16384}; ++c;
  };
  add(W(3),  128, 0,   0,   128);  // 0:  wq1
  add(W(4),  128, 0,   0,   128);  // 1:  wk1
  add(W(5),  128, 0,   0,   128);  // 2:  wv1
  add(W(17), 128, 0,   0,   128);  // 3:  wk2
  add(W(18), 128, 0,   0,   128);  // 4:  wv2
  add(W(6),  128, 0,   0,   128);  // 5:  wo1
  add(W(8),  256, 0,   0,   128);  // 6:  w1a lo cols
  add(W(8),  256, 0,   128, 128);  // 7:  w1a hi cols
  add(W(10), 128, 0,   0,   128);  // 8:  w1b k 0..127
  add(W(10), 128, 128, 0,   128);  // 9:  w1b k 128..255
  add(W(16), 128, 0,   0,   128);  // 10: wq2
  add(W(19), 128, 0,   0,   128);  // 11: wo2
  add(W(21), 256, 0,   0,   128);  // 12: w2a lo
  add(W(21), 256, 0,   128, 128);  // 13: w2a hi
  add(W(23), 128, 0,   0,   128);  // 14: w2b k0
  add(W(23), 128, 128, 0,   128);  // 15: w2b k1
  add(W(29), 64,  0,   0,   64);   // 16: w4
  pack_kernel<<<17, 256, 0, stream>>>(pa, wpack);

  k1_proj<<<(N + 63) / 64, 256, 0, stream>>>(feat, P, wpack, N);

  K2Args ka;
  ka.feat = feat; ka.nidx = nidx; ka.nval = nval; ka.flag = flag;
  ka.P = P; ka.wpack = wpack;
  ka.bo1 = W(7);  ka.b1a = W(9);  ka.b1b = W(11);
  ka.g1a = W(12); ka.be1a = W(13); ka.g1b = W(14); ka.be1b = W(15);
  ka.bo2 = W(20); ka.b2a = W(22); ka.b2b = W(24);
  ka.g2a = W(25); ka.be2a = W(26); ka.g2b = W(27); ka.be2b = W(28);
  ka.b4 = W(30); ka.out = (float*)d_out; ka.N = N;
  k2_fused<<<(N + 63) / 64, 256, 0, stream>>>(ka);
}